// Round 1
// baseline (1010.244 us; speedup 1.0000x reference)
//
#include <hip/hip_runtime.h>
#include <math.h>

#define Bb 4
#define Ss 2048
#define Dd 1024
#define Ee 8
#define Kk 2
#define FFf 4096
#define Tt (Bb*Ss)          // 8192 tokens
#define SLOTS (Tt*Kk)       // 16384 routed slots

#define BM 128
#define BN 128
#define BKs 32
#define KPAD 40             // +8 pad: 80B row stride, 16B-aligned, 2-way banks (free)

typedef unsigned short u16;
typedef unsigned int u32;
typedef __attribute__((ext_vector_type(8))) __bf16 bf16x8;
typedef __attribute__((ext_vector_type(4))) float f32x4;

__device__ __forceinline__ u16 f2bf(float f) {
  union { float f; u32 u; } v; v.f = f;
  u32 u = v.u;
  return (u16)((u + 0x7FFFu + ((u >> 16) & 1u)) >> 16);
}

// ---------------- gating: logits, top-2, softmax, counts ----------------
__global__ void gate_topk_kernel(const float* __restrict__ x,
                                 const float* __restrict__ gw,
                                 int* __restrict__ counts,
                                 int* __restrict__ tok_e,
                                 float* __restrict__ tok_w) {
  int wave = (int)((blockIdx.x * blockDim.x + threadIdx.x) >> 6);
  int lane = threadIdx.x & 63;
  if (wave >= Tt) return;
  const float* xrow = x + (size_t)wave * Dd;
  float p[Ee];
#pragma unroll
  for (int e = 0; e < Ee; e++) p[e] = 0.f;
  int d0 = lane * 16;
#pragma unroll
  for (int i = 0; i < 16; i++) {
    float xv = xrow[d0 + i];
    const float* g = gw + (size_t)(d0 + i) * Ee;
#pragma unroll
    for (int e = 0; e < Ee; e++) p[e] += xv * g[e];
  }
#pragma unroll
  for (int e = 0; e < Ee; e++) {
    for (int off = 32; off > 0; off >>= 1) p[e] += __shfl_xor(p[e], off, 64);
  }
  if (lane == 0) {
    int e0 = 0; float v0 = p[0];
#pragma unroll
    for (int e = 1; e < Ee; e++) if (p[e] > v0) { v0 = p[e]; e0 = e; }
    int e1 = -1; float v1 = -INFINITY;
#pragma unroll
    for (int e = 0; e < Ee; e++) if (e != e0 && p[e] > v1) { v1 = p[e]; e1 = e; }
    float w0 = 1.f / (1.f + expf(v1 - v0));
    float w1 = 1.f - w0;
    tok_e[wave * 2 + 0] = e0; tok_e[wave * 2 + 1] = e1;
    tok_w[wave * 2 + 0] = w0; tok_w[wave * 2 + 1] = w1;
    atomicAdd(&counts[e0], 1);
    atomicAdd(&counts[e1], 1);
  }
}

// ---------------- x -> bf16 ----------------
__global__ void xb_convert_kernel(const float* __restrict__ x, u16* __restrict__ xb) {
  int i = blockIdx.x * blockDim.x + threadIdx.x;   // 8 elems per thread
  const float* s = x + (size_t)i * 8;
  f32x4 v0 = *(const f32x4*)(s);
  f32x4 v1 = *(const f32x4*)(s + 4);
  uint4 o;
  o.x = (u32)f2bf(v0[0]) | ((u32)f2bf(v0[1]) << 16);
  o.y = (u32)f2bf(v0[2]) | ((u32)f2bf(v0[3]) << 16);
  o.z = (u32)f2bf(v1[0]) | ((u32)f2bf(v1[1]) << 16);
  o.w = (u32)f2bf(v1[2]) | ((u32)f2bf(v1[3]) << 16);
  *(uint4*)(xb + (size_t)i * 8) = o;
}

// ---------------- scan (E=8, 1 thread) ----------------
__global__ void scan_kernel(const int* __restrict__ counts,
                            int* __restrict__ offsets, int* __restrict__ cursors) {
  if (threadIdx.x == 0 && blockIdx.x == 0) {
    int acc = 0;
    for (int e = 0; e < Ee; e++) { offsets[e] = acc; cursors[e] = acc; acc += counts[e]; }
  }
}

// ---------------- scatter tokens into per-expert slot lists ----------------
__global__ void scatter_kernel(const int* __restrict__ tok_e, const float* __restrict__ tok_w,
                               int* __restrict__ cursors,
                               int* __restrict__ slot_token, float* __restrict__ slot_w) {
  int t = blockIdx.x * blockDim.x + threadIdx.x;
  if (t >= Tt) return;
#pragma unroll
  for (int k = 0; k < Kk; k++) {
    int e = tok_e[t * 2 + k];
    int pos = atomicAdd(&cursors[e], 1);
    slot_token[pos] = t;
    slot_w[pos] = tok_w[t * 2 + k];
  }
}

// ---------------- GEMM1: h = silu(x_gathered @ w1[e] + b1[e]) ----------------
__global__ __launch_bounds__(256) void gemm1_kernel(
    const u16* __restrict__ xb, const float* __restrict__ w1,
    const float* __restrict__ b1, const int* __restrict__ offsets,
    const int* __restrict__ counts, const int* __restrict__ slot_token,
    u16* __restrict__ h) {
  int e = blockIdx.z;
  int cnt = counts[e];
  int rb = blockIdx.y;
  if (rb * BM >= cnt) return;
  int off = offsets[e];
  int n0 = blockIdx.x * BN;
  const float* W = w1 + (size_t)e * Dd * FFf;

  __shared__ u16 As[BM][KPAD];
  __shared__ u16 Bs[BN][KPAD];

  int tid = threadIdx.x;
  int lane = tid & 63, wave = tid >> 6;
  int wm = (wave >> 1) * 64, wn = (wave & 1) * 64;
  int lr = lane & 15, g = lane >> 4;

  // A staging: 2 threads/row, 16 bf16 each
  int ar = tid >> 1;
  int akh = (tid & 1) * 16;
  int aslot = off + rb * BM + ar;
  int amax = off + cnt - 1;
  int atok = slot_token[aslot > amax ? amax : aslot];
  const u16* asrc = xb + (size_t)atok * Dd;

  // B staging: transpose f32 [K][N] -> LDS [N][K] bf16
  int bn = tid & 127;
  int bkh = (tid >> 7) * 16;

  f32x4 acc[4][4];
#pragma unroll
  for (int i = 0; i < 4; i++)
#pragma unroll
    for (int j = 0; j < 4; j++) acc[i][j] = (f32x4)(0.0f);

  for (int k0 = 0; k0 < Dd; k0 += BKs) {
    __syncthreads();
    { // A
      const uint4* s = (const uint4*)(asrc + k0 + akh);
      *(uint4*)&As[ar][akh] = s[0];
      *(uint4*)&As[ar][akh + 8] = s[1];
    }
    { // B (16 strided f32 loads, coalesced across lanes along n)
      const float* s = W + (size_t)(k0 + bkh) * FFf + n0 + bn;
      float v[16];
#pragma unroll
      for (int i = 0; i < 16; i++) v[i] = s[(size_t)i * FFf];
      uint4 w0, w1p;
      w0.x = (u32)f2bf(v[0]) | ((u32)f2bf(v[1]) << 16);
      w0.y = (u32)f2bf(v[2]) | ((u32)f2bf(v[3]) << 16);
      w0.z = (u32)f2bf(v[4]) | ((u32)f2bf(v[5]) << 16);
      w0.w = (u32)f2bf(v[6]) | ((u32)f2bf(v[7]) << 16);
      w1p.x = (u32)f2bf(v[8]) | ((u32)f2bf(v[9]) << 16);
      w1p.y = (u32)f2bf(v[10]) | ((u32)f2bf(v[11]) << 16);
      w1p.z = (u32)f2bf(v[12]) | ((u32)f2bf(v[13]) << 16);
      w1p.w = (u32)f2bf(v[14]) | ((u32)f2bf(v[15]) << 16);
      *(uint4*)&Bs[bn][bkh] = w0;
      *(uint4*)&Bs[bn][bkh + 8] = w1p;
    }
    __syncthreads();
    bf16x8 a[4], b[4];
#pragma unroll
    for (int i = 0; i < 4; i++) a[i] = *reinterpret_cast<const bf16x8*>(&As[wm + i * 16 + lr][g * 8]);
#pragma unroll
    for (int j = 0; j < 4; j++) b[j] = *reinterpret_cast<const bf16x8*>(&Bs[wn + j * 16 + lr][g * 8]);
#pragma unroll
    for (int i = 0; i < 4; i++)
#pragma unroll
      for (int j = 0; j < 4; j++)
        acc[i][j] = __builtin_amdgcn_mfma_f32_16x16x32_bf16(a[i], b[j], acc[i][j], 0, 0, 0);
  }

  int rlim = cnt - rb * BM;
#pragma unroll
  for (int i = 0; i < 4; i++) {
    int mbase = wm + i * 16 + g * 4;
#pragma unroll
    for (int t = 0; t < 4; t++) {
      int m = mbase + t;
      if (m < rlim) {
        int slot = off + rb * BM + m;
        u16* hrow = h + (size_t)slot * FFf;
#pragma unroll
        for (int j = 0; j < 4; j++) {
          int n = n0 + wn + j * 16 + lr;
          float v = acc[i][j][t] + b1[e * FFf + n];
          float sv = v / (1.f + expf(-v));   // silu
          hrow[n] = f2bf(sv);
        }
      }
    }
  }
}

// ---------------- GEMM2: out[token] += w_slot * (h @ w2[e] + b2[e]) ----------------
__global__ __launch_bounds__(256) void gemm2_kernel(
    const u16* __restrict__ h, const float* __restrict__ w2,
    const float* __restrict__ b2, const int* __restrict__ offsets,
    const int* __restrict__ counts, const int* __restrict__ slot_token,
    const float* __restrict__ slot_w, float* __restrict__ out) {
  int e = blockIdx.z;
  int cnt = counts[e];
  int rb = blockIdx.y;
  if (rb * BM >= cnt) return;
  int off = offsets[e];
  int n0 = blockIdx.x * BN;
  const float* W = w2 + (size_t)e * FFf * Dd;

  __shared__ u16 As[BM][KPAD];
  __shared__ u16 Bs[BN][KPAD];

  int tid = threadIdx.x;
  int lane = tid & 63, wave = tid >> 6;
  int wm = (wave >> 1) * 64, wn = (wave & 1) * 64;
  int lr = lane & 15, g = lane >> 4;

  int ar = tid >> 1;
  int akh = (tid & 1) * 16;
  int aslot = off + rb * BM + ar;
  int amax = off + cnt - 1;
  int srow = aslot > amax ? amax : aslot;
  const u16* asrc = h + (size_t)srow * FFf;

  int bn = tid & 127;
  int bkh = (tid >> 7) * 16;

  f32x4 acc[4][4];
#pragma unroll
  for (int i = 0; i < 4; i++)
#pragma unroll
    for (int j = 0; j < 4; j++) acc[i][j] = (f32x4)(0.0f);

  for (int k0 = 0; k0 < FFf; k0 += BKs) {
    __syncthreads();
    {
      const uint4* s = (const uint4*)(asrc + k0 + akh);
      *(uint4*)&As[ar][akh] = s[0];
      *(uint4*)&As[ar][akh + 8] = s[1];
    }
    {
      const float* s = W + (size_t)(k0 + bkh) * Dd + n0 + bn;
      float v[16];
#pragma unroll
      for (int i = 0; i < 16; i++) v[i] = s[(size_t)i * Dd];
      uint4 w0, w1p;
      w0.x = (u32)f2bf(v[0]) | ((u32)f2bf(v[1]) << 16);
      w0.y = (u32)f2bf(v[2]) | ((u32)f2bf(v[3]) << 16);
      w0.z = (u32)f2bf(v[4]) | ((u32)f2bf(v[5]) << 16);
      w0.w = (u32)f2bf(v[6]) | ((u32)f2bf(v[7]) << 16);
      w1p.x = (u32)f2bf(v[8]) | ((u32)f2bf(v[9]) << 16);
      w1p.y = (u32)f2bf(v[10]) | ((u32)f2bf(v[11]) << 16);
      w1p.z = (u32)f2bf(v[12]) | ((u32)f2bf(v[13]) << 16);
      w1p.w = (u32)f2bf(v[14]) | ((u32)f2bf(v[15]) << 16);
      *(uint4*)&Bs[bn][bkh] = w0;
      *(uint4*)&Bs[bn][bkh + 8] = w1p;
    }
    __syncthreads();
    bf16x8 a[4], b[4];
#pragma unroll
    for (int i = 0; i < 4; i++) a[i] = *reinterpret_cast<const bf16x8*>(&As[wm + i * 16 + lr][g * 8]);
#pragma unroll
    for (int j = 0; j < 4; j++) b[j] = *reinterpret_cast<const bf16x8*>(&Bs[wn + j * 16 + lr][g * 8]);
#pragma unroll
    for (int i = 0; i < 4; i++)
#pragma unroll
      for (int j = 0; j < 4; j++)
        acc[i][j] = __builtin_amdgcn_mfma_f32_16x16x32_bf16(a[i], b[j], acc[i][j], 0, 0, 0);
  }

  int rlim = cnt - rb * BM;
#pragma unroll
  for (int i = 0; i < 4; i++) {
    int mbase = wm + i * 16 + g * 4;
#pragma unroll
    for (int t = 0; t < 4; t++) {
      int m = mbase + t;
      if (m < rlim) {
        int slot = off + rb * BM + m;
        int tok = slot_token[slot];
        float wgt = slot_w[slot];
        float* orow = out + (size_t)tok * Dd;
#pragma unroll
        for (int j = 0; j < 4; j++) {
          int n = n0 + wn + j * 16 + lr;
          float v = (acc[i][j][t] + b2[e * Dd + n]) * wgt;
          atomicAdd(&orow[n], v);
        }
      }
    }
  }
}

extern "C" void kernel_launch(void* const* d_in, const int* in_sizes, int n_in,
                              void* d_out, int out_size, void* d_ws, size_t ws_size,
                              hipStream_t stream) {
  const float* x  = (const float*)d_in[0];
  const float* gw = (const float*)d_in[1];
  const float* w1 = (const float*)d_in[2];
  const float* b1 = (const float*)d_in[3];
  const float* w2 = (const float*)d_in[4];
  const float* b2 = (const float*)d_in[5];
  float* out = (float*)d_out;

  char* ws = (char*)d_ws;
  size_t off_counts = 0;
  size_t off_offsets = 256;
  size_t off_cursors = 512;
  size_t off_tok_e = 1024;
  size_t off_tok_w = off_tok_e + (size_t)Tt * 2 * 4;
  size_t off_slot_token = off_tok_w + (size_t)Tt * 2 * 4;
  size_t off_slot_w = off_slot_token + (size_t)SLOTS * 4;
  size_t off_xb = off_slot_w + (size_t)SLOTS * 4;
  size_t off_h = off_xb + (size_t)Tt * Dd * 2;
  size_t need = off_h + (size_t)SLOTS * FFf * 2;
  if (ws_size < need) return;  // ws too small: fail validation visibly, no OOB

  int* counts     = (int*)(ws + off_counts);
  int* offsets    = (int*)(ws + off_offsets);
  int* cursors    = (int*)(ws + off_cursors);
  int* tok_e      = (int*)(ws + off_tok_e);
  float* tok_w    = (float*)(ws + off_tok_w);
  int* slot_token = (int*)(ws + off_slot_token);
  float* slot_w   = (float*)(ws + off_slot_w);
  u16* xb         = (u16*)(ws + off_xb);
  u16* h          = (u16*)(ws + off_h);

  hipMemsetAsync(ws, 0, 1024, stream);                                  // counts/offsets/cursors
  hipMemsetAsync(d_out, 0, (size_t)out_size * sizeof(float), stream);   // atomic accum target

  gate_topk_kernel<<<Tt / 4, 256, 0, stream>>>(x, gw, counts, tok_e, tok_w);
  xb_convert_kernel<<<(Tt * Dd / 8) / 256, 256, 0, stream>>>(x, xb);
  scan_kernel<<<1, 64, 0, stream>>>(counts, offsets, cursors);
  scatter_kernel<<<Tt / 256, 256, 0, stream>>>(tok_e, tok_w, cursors, slot_token, slot_w);

  dim3 g1(FFf / BN, Tt / BM, Ee);   // (32, 64, 8); early-exit beyond counts[e]
  gemm1_kernel<<<g1, 256, 0, stream>>>(xb, w1, b1, offsets, counts, slot_token, h);

  dim3 g2(Dd / BN, Tt / BM, Ee);    // (8, 64, 8)
  gemm2_kernel<<<g2, 256, 0, stream>>>(h, w2, b2, offsets, counts, slot_token, slot_w, out);
}

// Round 2
// 840.607 us; speedup vs baseline: 1.2018x; 1.2018x over previous
//
#include <hip/hip_runtime.h>
#include <math.h>

#define Tt 8192             // tokens (B*S)
#define Dd 1024
#define Ee 8
#define FFf 4096
#define SLOTS (Tt*2)

typedef unsigned short u16;
typedef unsigned int u32;
typedef __attribute__((ext_vector_type(8))) __bf16 bf16x8;
typedef __attribute__((ext_vector_type(4))) float f32x4;

__device__ __forceinline__ u16 f2bf(float f) {
  union { float f; u32 u; } v; v.f = f;
  u32 u = v.u;
  return (u16)((u + 0x7FFFu + ((u >> 16) & 1u)) >> 16);
}
__device__ __forceinline__ float bf2f(u16 h) {
  union { u32 u; float f; } v; v.u = ((u32)h) << 16; return v.f;
}
__device__ __forceinline__ void gl2lds16(const u16* g, u16* l) {
  __builtin_amdgcn_global_load_lds((const __attribute__((address_space(1))) void*)g,
                                   (__attribute__((address_space(3))) void*)l, 16, 0, 0);
}

// ---------------- gating: logits, top-2, softmax, counts ----------------
__global__ void gate_topk_kernel(const float* __restrict__ x,
                                 const float* __restrict__ gw,
                                 int* __restrict__ counts,
                                 int* __restrict__ tok_e,
                                 float* __restrict__ tok_w) {
  int wave = (int)((blockIdx.x * blockDim.x + threadIdx.x) >> 6);
  int lane = threadIdx.x & 63;
  if (wave >= Tt) return;
  const float* xrow = x + (size_t)wave * Dd;
  float p[Ee];
#pragma unroll
  for (int e = 0; e < Ee; e++) p[e] = 0.f;
  int d0 = lane * 16;
#pragma unroll
  for (int i = 0; i < 16; i++) {
    float xv = xrow[d0 + i];
    const float* g = gw + (size_t)(d0 + i) * Ee;
#pragma unroll
    for (int e = 0; e < Ee; e++) p[e] += xv * g[e];
  }
#pragma unroll
  for (int e = 0; e < Ee; e++) {
    for (int off = 32; off > 0; off >>= 1) p[e] += __shfl_xor(p[e], off, 64);
  }
  if (lane == 0) {
    int e0 = 0; float v0 = p[0];
#pragma unroll
    for (int e = 1; e < Ee; e++) if (p[e] > v0) { v0 = p[e]; e0 = e; }
    int e1 = -1; float v1 = -INFINITY;
#pragma unroll
    for (int e = 0; e < Ee; e++) if (e != e0 && p[e] > v1) { v1 = p[e]; e1 = e; }
    float w0 = 1.f / (1.f + expf(v1 - v0));
    float w1 = 1.f - w0;
    tok_e[wave * 2 + 0] = e0; tok_e[wave * 2 + 1] = e1;
    tok_w[wave * 2 + 0] = w0; tok_w[wave * 2 + 1] = w1;
    atomicAdd(&counts[e0], 1);
    atomicAdd(&counts[e1], 1);
  }
}

// ---------------- x -> bf16 ----------------
__global__ void xb_convert_kernel(const float* __restrict__ x, u16* __restrict__ xb) {
  int i = blockIdx.x * blockDim.x + threadIdx.x;   // 8 elems per thread
  const float* s = x + (size_t)i * 8;
  f32x4 v0 = *(const f32x4*)(s);
  f32x4 v1 = *(const f32x4*)(s + 4);
  uint4 o;
  o.x = (u32)f2bf(v0[0]) | ((u32)f2bf(v0[1]) << 16);
  o.y = (u32)f2bf(v0[2]) | ((u32)f2bf(v0[3]) << 16);
  o.z = (u32)f2bf(v1[0]) | ((u32)f2bf(v1[1]) << 16);
  o.w = (u32)f2bf(v1[2]) | ((u32)f2bf(v1[3]) << 16);
  *(uint4*)(xb + (size_t)i * 8) = o;
}

// ---------------- weight transpose+convert: src f32 [E][R][C] -> dst bf16 [E][C][R] ----------------
__global__ __launch_bounds__(256) void wconv_kernel(const float* __restrict__ src,
                                                    u16* __restrict__ dst, int R, int C) {
  __shared__ u16 t[64][72];   // +8 pad
  int e = blockIdx.z;
  size_t ebase = (size_t)e * R * C;
  int r0 = blockIdx.y * 64, c0 = blockIdx.x * 64;
  int tid = threadIdx.x;
  int row = tid >> 2, seg = tid & 3;
  const float* sp = src + ebase + (size_t)(r0 + row) * C + c0 + seg * 16;
  f32x4 v0 = *(const f32x4*)(sp);
  f32x4 v1 = *(const f32x4*)(sp + 4);
  f32x4 v2 = *(const f32x4*)(sp + 8);
  f32x4 v3 = *(const f32x4*)(sp + 12);
  uint4 o0, o1;
  o0.x = (u32)f2bf(v0[0]) | ((u32)f2bf(v0[1]) << 16);
  o0.y = (u32)f2bf(v0[2]) | ((u32)f2bf(v0[3]) << 16);
  o0.z = (u32)f2bf(v1[0]) | ((u32)f2bf(v1[1]) << 16);
  o0.w = (u32)f2bf(v1[2]) | ((u32)f2bf(v1[3]) << 16);
  o1.x = (u32)f2bf(v2[0]) | ((u32)f2bf(v2[1]) << 16);
  o1.y = (u32)f2bf(v2[2]) | ((u32)f2bf(v2[3]) << 16);
  o1.z = (u32)f2bf(v3[0]) | ((u32)f2bf(v3[1]) << 16);
  o1.w = (u32)f2bf(v3[2]) | ((u32)f2bf(v3[3]) << 16);
  *(uint4*)&t[row][seg * 16] = o0;
  *(uint4*)&t[row][seg * 16 + 8] = o1;
  __syncthreads();
  u32 w[8];
#pragma unroll
  for (int i = 0; i < 8; i++)
    w[i] = (u32)t[seg * 16 + 2 * i][row] | ((u32)t[seg * 16 + 2 * i + 1][row] << 16);
  u16* dp = dst + ebase + (size_t)(c0 + row) * R + r0 + seg * 16;
  uint4 d0, d1;
  d0.x = w[0]; d0.y = w[1]; d0.z = w[2]; d0.w = w[3];
  d1.x = w[4]; d1.y = w[5]; d1.z = w[6]; d1.w = w[7];
  *(uint4*)dp = d0;
  *(uint4*)(dp + 8) = d1;
}

// ---------------- scan (E=8, 1 thread) ----------------
__global__ void scan_kernel(const int* __restrict__ counts,
                            int* __restrict__ offsets, int* __restrict__ cursors) {
  if (threadIdx.x == 0 && blockIdx.x == 0) {
    int acc = 0;
    for (int e = 0; e < Ee; e++) { offsets[e] = acc; cursors[e] = acc; acc += counts[e]; }
  }
}

// ---------------- scatter tokens into per-expert slot lists ----------------
__global__ void scatter_kernel(const int* __restrict__ tok_e, const float* __restrict__ tok_w,
                               int* __restrict__ cursors,
                               int* __restrict__ slot_token, float* __restrict__ slot_w,
                               int* __restrict__ tok_slot) {
  int t = blockIdx.x * blockDim.x + threadIdx.x;
  if (t >= Tt) return;
#pragma unroll
  for (int k = 0; k < 2; k++) {
    int e = tok_e[t * 2 + k];
    int pos = atomicAdd(&cursors[e], 1);
    slot_token[pos] = t;
    slot_w[pos] = tok_w[t * 2 + k];
    tok_slot[t * 2 + k] = pos;
  }
}

// ---------------- grouped GEMM, m97 structure ----------------
// C = Agathered @ BT^T ; BT is [E][NDIM][KDIM] bf16 (pre-transposed).
// EPI 0: silu(acc + bias) -> O16 (h).  EPI 1: (acc+bias)*wgt -> O16 (y).
// EPI 2: (acc+bias)*wgt atomicAdd -> Of (out).
template<int KDIM, int NDIM, int EPI, int GATHER>
__global__ __launch_bounds__(256) void moe_gemm(
    const u16* __restrict__ A, const u16* __restrict__ BT,
    const float* __restrict__ bias,
    const int* __restrict__ offsets, const int* __restrict__ counts,
    const int* __restrict__ slot_token, const float* __restrict__ slot_w,
    u16* __restrict__ O16, float* __restrict__ Of) {
  int e = blockIdx.z;
  int cnt = counts[e];
  int rb = blockIdx.y;
  if (rb * 128 >= cnt) return;
  int off = offsets[e];
  int n0 = blockIdx.x * 128;

  __shared__ u16 As[128 * 32];   // [row][k], 64B rows, linear (gl2lds dest)
  __shared__ u16 Bs[128 * 32];

  int tid = threadIdx.x;
  int lane = tid & 63, wave = tid >> 6;
  int wm = (wave >> 1) * 64, wn = (wave & 1) * 64;
  int lr = lane & 15, g = lane >> 4;

  int kseg = (lane & 3) * 8;
  const u16* BTe = BT + (size_t)e * NDIM * KDIM;
  const u16* baseA[2]; const u16* baseB[2];
  u16* ldsA[2]; u16* ldsB[2];
#pragma unroll
  for (int q = 0; q < 2; q++) {
    int chunk = wave * 2 + q;
    int row = chunk * 16 + (lane >> 2);
    int slotRow = off + rb * 128 + row;
    int amax = off + cnt - 1;
    if (slotRow > amax) slotRow = amax;
    int arow = GATHER ? slot_token[slotRow] : slotRow;
    baseA[q] = A + (size_t)arow * KDIM + kseg;
    baseB[q] = BTe + (size_t)(n0 + row) * KDIM + kseg;
    ldsA[q] = As + chunk * 512;   // 16 rows * 32 u16
    ldsB[q] = Bs + chunk * 512;
  }

  f32x4 acc[4][4];
#pragma unroll
  for (int i = 0; i < 4; i++)
#pragma unroll
    for (int j = 0; j < 4; j++) acc[i][j] = (f32x4)(0.0f);

  for (int k0 = 0; k0 < KDIM; k0 += 32) {
    __syncthreads();              // prior ds_reads done before overwrite
    gl2lds16(baseA[0] + k0, ldsA[0]);
    gl2lds16(baseA[1] + k0, ldsA[1]);
    gl2lds16(baseB[0] + k0, ldsB[0]);
    gl2lds16(baseB[1] + k0, ldsB[1]);
    __syncthreads();              // vmcnt(0) drain before use
    bf16x8 a[4], b[4];
#pragma unroll
    for (int i = 0; i < 4; i++)
      a[i] = *reinterpret_cast<const bf16x8*>(&As[(wm + i * 16 + lr) * 32 + g * 8]);
#pragma unroll
    for (int j = 0; j < 4; j++)
      b[j] = *reinterpret_cast<const bf16x8*>(&Bs[(wn + j * 16 + lr) * 32 + g * 8]);
#pragma unroll
    for (int i = 0; i < 4; i++)
#pragma unroll
      for (int j = 0; j < 4; j++)
        acc[i][j] = __builtin_amdgcn_mfma_f32_16x16x32_bf16(a[i], b[j], acc[i][j], 0, 0, 0);
  }

  int rlim = cnt - rb * 128;
#pragma unroll
  for (int i = 0; i < 4; i++) {
    int mbase = wm + i * 16 + g * 4;
#pragma unroll
    for (int t = 0; t < 4; t++) {
      int m = mbase + t;
      if (m < rlim) {
        int slot = off + rb * 128 + m;
#pragma unroll
        for (int j = 0; j < 4; j++) {
          int n = n0 + wn + j * 16 + lr;
          float v = acc[i][j][t] + bias[e * NDIM + n];
          if (EPI == 0) {
            float sv = v / (1.f + expf(-v));   // silu
            O16[(size_t)slot * NDIM + n] = f2bf(sv);
          } else if (EPI == 1) {
            float wv = v * slot_w[slot];
            O16[(size_t)slot * NDIM + n] = f2bf(wv);
          } else {
            int tok = slot_token[slot];
            atomicAdd(Of + (size_t)tok * NDIM + n, v * slot_w[slot]);
          }
        }
      }
    }
  }
}

// ---------------- combine: out[t] = y[slot0] + y[slot1] ----------------
__global__ void combine_kernel(const u16* __restrict__ y, const int* __restrict__ tok_slot,
                               float* __restrict__ out) {
  int gid = blockIdx.x * blockDim.x + threadIdx.x;  // Tt*128 threads, 8 elems each
  int t = gid >> 7;
  int seg = gid & 127;
  int s0 = tok_slot[t * 2 + 0], s1 = tok_slot[t * 2 + 1];
  uint4 a = *(const uint4*)(y + (size_t)s0 * Dd + seg * 8);
  uint4 b = *(const uint4*)(y + (size_t)s1 * Dd + seg * 8);
  f32x4 o0, o1;
  o0[0] = bf2f((u16)a.x) + bf2f((u16)b.x);
  o0[1] = bf2f((u16)(a.x >> 16)) + bf2f((u16)(b.x >> 16));
  o0[2] = bf2f((u16)a.y) + bf2f((u16)b.y);
  o0[3] = bf2f((u16)(a.y >> 16)) + bf2f((u16)(b.y >> 16));
  o1[0] = bf2f((u16)a.z) + bf2f((u16)b.z);
  o1[1] = bf2f((u16)(a.z >> 16)) + bf2f((u16)(b.z >> 16));
  o1[2] = bf2f((u16)a.w) + bf2f((u16)b.w);
  o1[3] = bf2f((u16)(a.w >> 16)) + bf2f((u16)(b.w >> 16));
  float* op = out + (size_t)t * Dd + seg * 8;
  *(f32x4*)op = o0;
  *(f32x4*)(op + 4) = o1;
}

extern "C" void kernel_launch(void* const* d_in, const int* in_sizes, int n_in,
                              void* d_out, int out_size, void* d_ws, size_t ws_size,
                              hipStream_t stream) {
  const float* x  = (const float*)d_in[0];
  const float* gw = (const float*)d_in[1];
  const float* w1 = (const float*)d_in[2];
  const float* b1 = (const float*)d_in[3];
  const float* w2 = (const float*)d_in[4];
  const float* b2 = (const float*)d_in[5];
  float* out = (float*)d_out;

  char* ws = (char*)d_ws;
  size_t off_counts = 0;
  size_t off_offsets = 256;
  size_t off_cursors = 512;
  size_t off_tok_e = 1024;
  size_t off_tok_w     = off_tok_e + (size_t)Tt * 2 * 4;
  size_t off_tok_slot  = off_tok_w + (size_t)Tt * 2 * 4;
  size_t off_slot_token= off_tok_slot + (size_t)Tt * 2 * 4;
  size_t off_slot_w    = off_slot_token + (size_t)SLOTS * 4;
  size_t off_xb        = off_slot_w + (size_t)SLOTS * 4;
  size_t off_h         = off_xb + (size_t)Tt * Dd * 2;
  size_t off_wT        = off_h + (size_t)SLOTS * FFf * 2;
  size_t off_y         = off_wT + (size_t)Ee * Dd * FFf * 2;
  size_t need_atomic   = off_y;
  size_t need_full     = off_y + (size_t)SLOTS * Dd * 2;
  if (ws_size < need_atomic) return;  // cannot run; fail visibly, no OOB
  int use_combine = (ws_size >= need_full) ? 1 : 0;

  int* counts     = (int*)(ws + off_counts);
  int* offsets    = (int*)(ws + off_offsets);
  int* cursors    = (int*)(ws + off_cursors);
  int* tok_e      = (int*)(ws + off_tok_e);
  float* tok_w    = (float*)(ws + off_tok_w);
  int* tok_slot   = (int*)(ws + off_tok_slot);
  int* slot_token = (int*)(ws + off_slot_token);
  float* slot_w   = (float*)(ws + off_slot_w);
  u16* xb         = (u16*)(ws + off_xb);
  u16* h          = (u16*)(ws + off_h);
  u16* wT         = (u16*)(ws + off_wT);
  u16* y          = (u16*)(ws + off_y);

  hipMemsetAsync(ws, 0, 1024, stream);   // counts/offsets/cursors

  gate_topk_kernel<<<Tt / 4, 256, 0, stream>>>(x, gw, counts, tok_e, tok_w);
  xb_convert_kernel<<<(Tt * Dd / 8) / 256, 256, 0, stream>>>(x, xb);
  scan_kernel<<<1, 64, 0, stream>>>(counts, offsets, cursors);
  scatter_kernel<<<Tt / 256, 256, 0, stream>>>(tok_e, tok_w, cursors, slot_token, slot_w, tok_slot);

  // w1 [E][D][FF] f32 -> wT [E][FF][D] bf16
  {
    dim3 gc(FFf / 64, Dd / 64, Ee);
    wconv_kernel<<<gc, 256, 0, stream>>>(w1, wT, Dd, FFf);
  }
  {
    dim3 g1(FFf / 128, Tt / 128, Ee);
    moe_gemm<Dd, FFf, 0, 1><<<g1, 256, 0, stream>>>(xb, wT, b1, offsets, counts,
                                                    slot_token, slot_w, h, nullptr);
  }
  // w2 [E][FF][D] f32 -> wT [E][D][FF] bf16 (buffer reuse; stream-serialized after gemm1)
  {
    dim3 gc(Dd / 64, FFf / 64, Ee);
    wconv_kernel<<<gc, 256, 0, stream>>>(w2, wT, FFf, Dd);
  }
  if (use_combine) {
    dim3 g2(Dd / 128, Tt / 128, Ee);
    moe_gemm<FFf, Dd, 1, 0><<<g2, 256, 0, stream>>>(h, wT, b2, offsets, counts,
                                                    slot_token, slot_w, y, nullptr);
    combine_kernel<<<(Tt * 128) / 256, 256, 0, stream>>>(y, tok_slot, out);
  } else {
    hipMemsetAsync(d_out, 0, (size_t)out_size * sizeof(float), stream);
    dim3 g2(Dd / 128, Tt / 128, Ee);
    moe_gemm<FFf, Dd, 2, 0><<<g2, 256, 0, stream>>>(h, wT, b2, offsets, counts,
                                                    slot_token, slot_w, nullptr, out);
  }
}